// Round 1
// baseline (116.811 us; speedup 1.0000x reference)
//
#include <hip/hip_runtime.h>

#define SS 4096
#define DD 64
#define NH 16
#define QBLK 64
#define NQB (SS / QBLK)   // 64
#define PK  72            // K-tile LDS pitch (bf16 elems), padded
#define PVT 68            // V^T-tile LDS pitch (bf16 elems), padded

typedef float  fx4   __attribute__((ext_vector_type(4)));
typedef __bf16 bf16x8 __attribute__((ext_vector_type(8)));
typedef __bf16 bf16x4 __attribute__((ext_vector_type(4)));
typedef short  sx4    __attribute__((ext_vector_type(4)));

__global__ __launch_bounds__(256, 4)
void attn_fwd_kernel(const float* __restrict__ Qg, const float* __restrict__ Kg,
                     const float* __restrict__ Vg, float* __restrict__ Og)
{
    __shared__ __bf16 lK[QBLK * PK];    // K tile, row-major [k][d]
    __shared__ __bf16 lVT[DD * PVT];    // V tile, transposed [d][k]

    const int tid  = threadIdx.x;
    const int wid  = tid >> 6;
    const int lane = tid & 63;
    const int lr   = lane & 15;
    const int g    = lane >> 4;

    const int h  = (int)(blockIdx.x) & (NH - 1);
    const int qb = NQB - 1 - (int)(blockIdx.x >> 4);   // heavy blocks first

    const float* Qh = Qg + (size_t)h * SS * DD;
    const float* Kh = Kg + (size_t)h * SS * DD;
    const float* Vh = Vg + (size_t)h * SS * DD;
    float*       Oh = Og + (size_t)h * SS * DD;

    const int q0   = qb * QBLK + wid * 16;   // this wave's first q row
    const int qrow = q0 + lr;                // this lane's softmax-stats row

    // ---- Q fragments (held all kernel), pre-scaled by 1/sqrt(64) ----
    // B-frag for swapped QK^T: lane holds Q[q0+lr][h2*32 + g*8 + j]
    bf16x8 qa[2];
#pragma unroll
    for (int h2 = 0; h2 < 2; ++h2) {
        const float* src = Qh + (size_t)qrow * DD + h2 * 32 + g * 8;
        fx4 f0 = *(const fx4*)(src);
        fx4 f1 = *(const fx4*)(src + 4);
        bf16x8 t;
#pragma unroll
        for (int j = 0; j < 4; ++j) {
            t[j]     = (__bf16)(f0[j] * 0.125f);
            t[j + 4] = (__bf16)(f1[j] * 0.125f);
        }
        qa[h2] = t;
    }

    // O accumulator: acc[d0][r] = O[q0 + 4g + r][d0*16 + lr]
    fx4 acc[4];
#pragma unroll
    for (int i = 0; i < 4; ++i) acc[i] = (fx4){0.f, 0.f, 0.f, 0.f};
    float m_run = -1e30f;
    float l_run = 0.f;

    const int ntiles = qb + 1;   // causal: KV tiles 0..qb
    for (int t = 0; t < ntiles; ++t) {
        const int kv0 = t * QBLK;

        __syncthreads();   // protect LDS from previous iteration's readers
        // ---- stage K (row-major) and V (transposed) into LDS, f32 -> bf16 ----
#pragma unroll
        for (int rep = 0; rep < 4; ++rep) {
            const int idx = rep * 256 + tid;        // 0..1023
            const int row = idx >> 4;               // 0..63 (k within tile)
            const int c4  = (idx & 15) << 2;        // d base, multiple of 4

            fx4 kf = *(const fx4*)(Kh + (size_t)(kv0 + row) * DD + c4);
            bf16x4 kb;
            kb[0] = (__bf16)kf[0]; kb[1] = (__bf16)kf[1];
            kb[2] = (__bf16)kf[2]; kb[3] = (__bf16)kf[3];
            *(bf16x4*)(&lK[row * PK + c4]) = kb;

            fx4 vf = *(const fx4*)(Vh + (size_t)(kv0 + row) * DD + c4);
            lVT[(c4 + 0) * PVT + row] = (__bf16)vf[0];
            lVT[(c4 + 1) * PVT + row] = (__bf16)vf[1];
            lVT[(c4 + 2) * PVT + row] = (__bf16)vf[2];
            lVT[(c4 + 3) * PVT + row] = (__bf16)vf[3];
        }
        __syncthreads();

        // ---- QK^T (swapped): S^T[k][q] so P rows land lane-local ----
        // s[ks][r] = S[q0+lr][kv0 + ks*16 + 4g + r]
        float s[4][4];
#pragma unroll
        for (int ks = 0; ks < 4; ++ks) {
            const bf16x8 ka0 = *(const bf16x8*)(&lK[(ks * 16 + lr) * PK + g * 8]);
            const bf16x8 ka1 = *(const bf16x8*)(&lK[(ks * 16 + lr) * PK + 32 + g * 8]);
            fx4 st = (fx4){0.f, 0.f, 0.f, 0.f};
            st = __builtin_amdgcn_mfma_f32_16x16x32_bf16(ka0, qa[0], st, 0, 0, 0);
            st = __builtin_amdgcn_mfma_f32_16x16x32_bf16(ka1, qa[1], st, 0, 0, 0);
#pragma unroll
            for (int r = 0; r < 4; ++r) s[ks][r] = st[r];
        }

        // ---- causal mask (only diagonal tile can violate) ----
        if (t == ntiles - 1) {
#pragma unroll
            for (int ks = 0; ks < 4; ++ks)
#pragma unroll
                for (int r = 0; r < 4; ++r) {
                    const int kk = kv0 + ks * 16 + 4 * g + r;
                    if (kk > qrow) s[ks][r] = -1e30f;
                }
        }

        // ---- online softmax (row q = q0+lr, spread over 4 lanes via g) ----
        float tmax = -1e30f;
#pragma unroll
        for (int ks = 0; ks < 4; ++ks)
#pragma unroll
            for (int r = 0; r < 4; ++r) tmax = fmaxf(tmax, s[ks][r]);
        tmax = fmaxf(tmax, __shfl_xor(tmax, 16));
        tmax = fmaxf(tmax, __shfl_xor(tmax, 32));
        const float m_new = fmaxf(m_run, tmax);
        const float alpha = __expf(m_run - m_new);

        float p[4][4];
        float psum = 0.f;
#pragma unroll
        for (int ks = 0; ks < 4; ++ks)
#pragma unroll
            for (int r = 0; r < 4; ++r) {
                p[ks][r] = __expf(s[ks][r] - m_new);
                psum += p[ks][r];
            }
        psum += __shfl_xor(psum, 16);
        psum += __shfl_xor(psum, 32);
        l_run = l_run * alpha + psum;
        m_run = m_new;

        // rescale O accumulator: row (4g+r)'s alpha lives in lane (4g+r)
        float av[4];
#pragma unroll
        for (int r = 0; r < 4; ++r) av[r] = __shfl(alpha, 4 * g + r);
#pragma unroll
        for (int d0 = 0; d0 < 4; ++d0) {
            fx4 a = acc[d0];
            a[0] *= av[0]; a[1] *= av[1]; a[2] *= av[2]; a[3] *= av[3];
            acc[d0] = a;
        }

        // ---- PV: A-frag (K=16) is exactly our lane-local P layout ----
#pragma unroll
        for (int ks = 0; ks < 4; ++ks) {
            sx4 pa;
#pragma unroll
            for (int j = 0; j < 4; ++j) {
                const __bf16 pb = (__bf16)p[ks][j];
                pa[j] = __builtin_bit_cast(short, pb);
            }
#pragma unroll
            for (int d0 = 0; d0 < 4; ++d0) {
                // B-frag: V[kv0 + ks*16 + 4g + j][d0*16 + lr] = VT[d0*16+lr][ks*16+4g+j]
                const sx4 vb = *(const sx4*)(&lVT[(d0 * 16 + lr) * PVT + ks * 16 + 4 * g]);
                acc[d0] = __builtin_amdgcn_mfma_f32_16x16x16bf16_1k(pa, vb, acc[d0], 0, 0, 0);
            }
        }
    }

    // ---- epilogue: normalize rows and store f32 ----
    const float linv = 1.f / l_run;
    float bv[4];
#pragma unroll
    for (int r = 0; r < 4; ++r) bv[r] = __shfl(linv, 4 * g + r);
#pragma unroll
    for (int d0 = 0; d0 < 4; ++d0)
#pragma unroll
        for (int r = 0; r < 4; ++r)
            Oh[(size_t)(q0 + 4 * g + r) * DD + d0 * 16 + lr] = acc[d0][r] * bv[r];
}

extern "C" void kernel_launch(void* const* d_in, const int* in_sizes, int n_in,
                              void* d_out, int out_size, void* d_ws, size_t ws_size,
                              hipStream_t stream)
{
    (void)in_sizes; (void)n_in; (void)d_ws; (void)ws_size; (void)out_size;
    const float* q = (const float*)d_in[0];
    const float* k = (const float*)d_in[1];
    const float* v = (const float*)d_in[2];
    float*       o = (float*)d_out;

    dim3 grid(NH * NQB);   // 1024 blocks
    dim3 block(256);       // 4 waves
    hipLaunchKernelGGL(attn_fwd_kernel, grid, block, 0, stream, q, k, v, o);
}